// Round 6
// baseline (282.767 us; speedup 1.0000x reference)
//
#include <hip/hip_runtime.h>
#include <math.h>

#define HDIM  512
#define NHEAD 8
#define HEADD 64
#define BATCH 4
#define SEQ   1024
#define RELN  2048
#define LOG2E 1.4426950408889634f

typedef __attribute__((ext_vector_type(8))) short s16x8;
typedef __attribute__((ext_vector_type(4))) float f32x4;

#define MFMA __builtin_amdgcn_mfma_f32_16x16x32_bf16

__device__ __forceinline__ unsigned short f2bf(float x) {
    unsigned u = __float_as_uint(x);
    u += 0x7fffu + ((u >> 16) & 1u);
    return (unsigned short)(u >> 16);
}
__device__ __forceinline__ float bf2f(unsigned short h) {
    return __uint_as_float(((unsigned)h) << 16);
}

// ================= prep: rel-embedding GEMV + weight split + key->bf16 ==============
__global__ __launch_bounds__(256) void prep_kernel(
    const float* __restrict__ w_r_w, const float* __restrict__ w_r_b,
    const float* __restrict__ key,
    const float* __restrict__ wq, const float* __restrict__ wv,
    unsigned short* __restrict__ relbf, unsigned short* __restrict__ kbf,
    unsigned short* __restrict__ wtq_hi, unsigned short* __restrict__ wtq_lo,
    unsigned short* __restrict__ wtv_hi, unsigned short* __restrict__ wtv_lo)
{
    __shared__ float emb_s[HDIM];
    __shared__ float part[4][64];
    __shared__ float T[64][68];
    const int bid = blockIdx.x;
    const int t = threadIdx.x;

    if (bid < RELN) {
        const int l = bid;
        const float pos  = (float)(l - SEQ);
        const float coef = (float)(-9.210340371976184 / 255.0);  // -ln(10000)/(half-1)
        {
            float fr  = expf((float)t * coef);
            float ang = pos * fr;
            emb_s[t]       = sinf(ang);
            emb_s[t + 256] = cosf(ang);
        }
        __syncthreads();
        const int d  = t & 63;
        const int ks = t >> 6;
        const float* wp = w_r_w + d;
        const int h0 = ks * 128;
        float a0 = 0.f, a1 = 0.f, a2 = 0.f, a3 = 0.f;
        #pragma unroll 8
        for (int h = 0; h < 128; h += 4) {
            a0 = fmaf(emb_s[h0 + h + 0], wp[(size_t)(h0 + h + 0) * HEADD], a0);
            a1 = fmaf(emb_s[h0 + h + 1], wp[(size_t)(h0 + h + 1) * HEADD], a1);
            a2 = fmaf(emb_s[h0 + h + 2], wp[(size_t)(h0 + h + 2) * HEADD], a2);
            a3 = fmaf(emb_s[h0 + h + 3], wp[(size_t)(h0 + h + 3) * HEADD], a3);
        }
        part[ks][d] = (a0 + a1) + (a2 + a3);
        __syncthreads();
        if (ks == 0) {
            float acc = part[0][d] + part[1][d] + part[2][d] + part[3][d] + w_r_b[d];
            relbf[(size_t)l * HEADD + d] = f2bf(acc);
        }
    } else if (bid < RELN + 128) {
        const int idx = bid - RELN;
        const int z = idx >> 6, rem = idx & 63;
        const int by = rem >> 3, bx = rem & 7;
        const float* W = z ? wv : wq;
        unsigned short* Ohi = z ? wtv_hi : wtq_hi;
        unsigned short* Olo = z ? wtv_lo : wtq_lo;
        const int k0 = by * 64, n0 = bx * 64;
        const int r = t >> 2, c16 = (t & 3) * 16;
        #pragma unroll
        for (int u = 0; u < 4; ++u) {
            float4 v = *(const float4*)(W + (size_t)(k0 + r) * HDIM + n0 + c16 + u * 4);
            *(float4*)&T[r][c16 + u * 4] = v;
        }
        __syncthreads();
        __align__(16) unsigned short hi[16], lo[16];
        #pragma unroll
        for (int u = 0; u < 16; ++u) {
            float x = T[c16 + u][r];
            unsigned short h = f2bf(x);
            hi[u] = h;
            lo[u] = f2bf(x - bf2f(h));
        }
        size_t base = (size_t)(n0 + r) * HDIM + k0 + c16;
        *(uint4*)(Ohi + base)     = *(uint4*)&hi[0];
        *(uint4*)(Ohi + base + 8) = *(uint4*)&hi[8];
        *(uint4*)(Olo + base)     = *(uint4*)&lo[0];
        *(uint4*)(Olo + base + 8) = *(uint4*)&lo[8];
    } else {
        const int cid = bid - RELN - 128;
        const int i = (cid * 256 + t) * 8;
        float4 v0 = *(const float4*)(key + i);
        float4 v1 = *(const float4*)(key + i + 4);
        __align__(16) unsigned short h[8];
        h[0] = f2bf(v0.x); h[1] = f2bf(v0.y); h[2] = f2bf(v0.z); h[3] = f2bf(v0.w);
        h[4] = f2bf(v1.x); h[5] = f2bf(v1.y); h[6] = f2bf(v1.z); h[7] = f2bf(v1.w);
        *(uint4*)(kbf + i) = *(uint4*)h;
    }
}

// ============ merged projections: q (+rrb/+rwb) and v (transposed) ===============
__global__ __launch_bounds__(256) void proj_kernel(
    const float* __restrict__ query, const float* __restrict__ value,
    const unsigned short* __restrict__ wtq_hi, const unsigned short* __restrict__ wtq_lo,
    const unsigned short* __restrict__ wtv_hi, const unsigned short* __restrict__ wtv_lo,
    const float* __restrict__ w_q_b, const float* __restrict__ w_v_b,
    const float* __restrict__ rrb, const float* __restrict__ rwb,
    unsigned short* __restrict__ qabf, unsigned short* __restrict__ qbbf,
    unsigned short* __restrict__ vTbuf)
{
    __shared__ unsigned short Ah[64][40], Al[64][40], Bh[64][40], Bl[64][40];
    __shared__ unsigned short Ls[64][72];
    const int mode = blockIdx.z;
    const float* A = mode ? value : query;
    const unsigned short* Wt_hi = mode ? wtv_hi : wtq_hi;
    const unsigned short* Wt_lo = mode ? wtv_lo : wtq_lo;
    const float* bias = mode ? w_v_b : w_q_b;

    const int t = threadIdx.x;
    const int w = t >> 6, l = t & 63, colA = l & 15, g = l >> 4, kg8 = g * 8;
    const int n0 = blockIdx.x * 64, m0 = blockIdx.y * 64;
    const int mi = w >> 1, ni = w & 1;
    const int sr = t >> 2, skc = (t & 3) * 8;
    f32x4 acc[2][2] = {};

    for (int k0 = 0; k0 < HDIM; k0 += 32) {
        {
            const float* ap = A + (size_t)(m0 + sr) * HDIM + k0 + skc;
            float4 x0 = *(const float4*)ap;
            float4 x1 = *(const float4*)(ap + 4);
            float xv[8] = {x0.x, x0.y, x0.z, x0.w, x1.x, x1.y, x1.z, x1.w};
            __align__(16) unsigned short hh[8], ll[8];
            #pragma unroll
            for (int u = 0; u < 8; ++u) {
                unsigned short h = f2bf(xv[u]);
                hh[u] = h;
                ll[u] = f2bf(xv[u] - bf2f(h));
            }
            *(uint4*)&Ah[sr][skc] = *(uint4*)hh;
            *(uint4*)&Al[sr][skc] = *(uint4*)ll;
            *(uint4*)&Bh[sr][skc] = *(const uint4*)(Wt_hi + (size_t)(n0 + sr) * HDIM + k0 + skc);
            *(uint4*)&Bl[sr][skc] = *(const uint4*)(Wt_lo + (size_t)(n0 + sr) * HDIM + k0 + skc);
        }
        __syncthreads();
        s16x8 ah[2], al[2], bh[2], bl[2];
        #pragma unroll
        for (int mt = 0; mt < 2; ++mt) {
            ah[mt] = *(const s16x8*)&Ah[mi * 32 + mt * 16 + colA][kg8];
            al[mt] = *(const s16x8*)&Al[mi * 32 + mt * 16 + colA][kg8];
        }
        #pragma unroll
        for (int nt = 0; nt < 2; ++nt) {
            bh[nt] = *(const s16x8*)&Bh[ni * 32 + nt * 16 + colA][kg8];
            bl[nt] = *(const s16x8*)&Bl[ni * 32 + nt * 16 + colA][kg8];
        }
        #pragma unroll
        for (int mt = 0; mt < 2; ++mt)
            #pragma unroll
            for (int nt = 0; nt < 2; ++nt) {
                acc[mt][nt] = MFMA(al[mt], bh[nt], acc[mt][nt], 0, 0, 0);
                acc[mt][nt] = MFMA(ah[mt], bl[nt], acc[mt][nt], 0, 0, 0);
                acc[mt][nt] = MFMA(ah[mt], bh[nt], acc[mt][nt], 0, 0, 0);
            }
        __syncthreads();
    }

    float bv[2], ev1[2], ev2[2];
    #pragma unroll
    for (int nt = 0; nt < 2; ++nt) {
        int gn = n0 + ni * 32 + nt * 16 + colA;
        bv[nt] = bias[gn];
        if (mode == 0) { ev1[nt] = rrb[gn]; ev2[nt] = rwb[gn]; }
    }

    if (mode == 0) {
        #pragma unroll
        for (int mt = 0; mt < 2; ++mt)
            #pragma unroll
            for (int nt = 0; nt < 2; ++nt)
                #pragma unroll
                for (int rr = 0; rr < 4; ++rr)
                    Ls[mi * 32 + mt * 16 + g * 4 + rr][ni * 32 + nt * 16 + colA] =
                        f2bf(acc[mt][nt][rr] + bv[nt] + ev1[nt]);
        __syncthreads();
        {
            int r = t >> 2, c = (t & 3) * 16;
            uint4 x0 = *(uint4*)&Ls[r][c];
            uint4 x1 = *(uint4*)&Ls[r][c + 8];
            *(uint4*)(qabf + (size_t)(m0 + r) * HDIM + n0 + c)     = x0;
            *(uint4*)(qabf + (size_t)(m0 + r) * HDIM + n0 + c + 8) = x1;
        }
        __syncthreads();
        #pragma unroll
        for (int mt = 0; mt < 2; ++mt)
            #pragma unroll
            for (int nt = 0; nt < 2; ++nt)
                #pragma unroll
                for (int rr = 0; rr < 4; ++rr)
                    Ls[mi * 32 + mt * 16 + g * 4 + rr][ni * 32 + nt * 16 + colA] =
                        f2bf(acc[mt][nt][rr] + bv[nt] + ev2[nt]);
        __syncthreads();
        {
            int r = t >> 2, c = (t & 3) * 16;
            uint4 x0 = *(uint4*)&Ls[r][c];
            uint4 x1 = *(uint4*)&Ls[r][c + 8];
            *(uint4*)(qbbf + (size_t)(m0 + r) * HDIM + n0 + c)     = x0;
            *(uint4*)(qbbf + (size_t)(m0 + r) * HDIM + n0 + c + 8) = x1;
        }
    } else {
        #pragma unroll
        for (int mt = 0; mt < 2; ++mt)
            #pragma unroll
            for (int nt = 0; nt < 2; ++nt)
                #pragma unroll
                for (int rr = 0; rr < 4; ++rr)
                    Ls[ni * 32 + nt * 16 + colA][mi * 32 + mt * 16 + g * 4 + rr] =
                        f2bf(acc[mt][nt][rr] + bv[nt]);
        __syncthreads();
        {
            int dl = t >> 2, c = (t & 3) * 16;
            int head = n0 >> 6;
            int bb = m0 >> 10, j0 = m0 & 1023;
            uint4 x0 = *(uint4*)&Ls[dl][c];
            uint4 x1 = *(uint4*)&Ls[dl][c + 8];
            size_t vbase = ((size_t)(bb * NHEAD + head) * HEADD + dl) * SEQ + j0 + c;
            *(uint4*)(vTbuf + vbase)     = x0;
            *(uint4*)(vTbuf + vbase + 8) = x1;
        }
    }
}

// ---------------- fused MFMA flash attention, wave-role split (r3 structure) ----------
// Delta vs r3 flash_v3: R2_s/R3_s LDS band staging removed; M2/M3 B-fragments are
// loaded directly from global relbf (L2-resident, 16B-aligned). Indices proven:
// l2 = SEQ+j0-i0-31+urow in [1,2048], l3 = SEQ+i0-j0-31+urow in [1,2048]; the 2048
// case is only urow=63 whose gather column (s in [0,62]) is never read; clamped anyway.
__global__ __launch_bounds__(256) void flash_v3(
    const unsigned short* __restrict__ kbf,
    const unsigned short* __restrict__ qabf,
    const unsigned short* __restrict__ qbbf,
    const unsigned short* __restrict__ vT,
    const unsigned short* __restrict__ relbf,
    const int* __restrict__ seqp,
    float* __restrict__ out)
{
    __shared__ unsigned short K_s[32][72];
    __shared__ unsigned short Vt_s[64][40];
    __shared__ unsigned short M2t_s[64][36];   // [u][i] transposed
    __shared__ unsigned short M3t_s[64][36];   // [u][j] transposed
    __shared__ unsigned short P_s[32][40];
    __shared__ float scale_s[32];
    __shared__ float lsum_s[32];

    const int t = threadIdx.x;
    const int w = t >> 6, l = t & 63, colA = l & 15, g = l >> 4, kg8 = g * 8;
    const int i0 = blockIdx.x * 32;
    const int n = blockIdx.y, b = blockIdx.z;
    const int S = seqp[0];

    const int qa_row = i0 + (w & 1) * 16 + colA;
    const int qb_row = i0 + (w == 3 ? 16 : 0) + colA;
    const s16x8* qaP = (const s16x8*)(qabf + ((size_t)(b * SEQ + qa_row) * HDIM + n * HEADD));
    const s16x8* qbP = (const s16x8*)(qbbf + ((size_t)(b * SEQ + qb_row) * HDIM + n * HEADD));
    const s16x8 qa0 = qaP[g], qa1 = qaP[g + 4];
    const s16x8 qb0 = qbP[g], qb1 = qbP[g + 4];

    float m_run[4] = {-1e30f, -1e30f, -1e30f, -1e30f};
    float l_run[4] = {0.f, 0.f, 0.f, 0.f};
    f32x4 o0 = {0.f, 0.f, 0.f, 0.f}, o1 = {0.f, 0.f, 0.f, 0.f};

    const int krow = t >> 3, kc8 = (t & 7) * 8;   // K staging 32x64
    const int vrow = t >> 2, vc8 = (t & 3) * 8;   // Vt staging 64x32
    const int orow = (w & 1) * 16;                // O row offset
    const int od   = (w >> 1) * 32;               // O d offset

    for (int j0 = 0; j0 < S; j0 += 32) {
        // ---- stage K, Vt ----
        *(uint4*)&K_s[krow][kc8] =
            *(const uint4*)(kbf + ((size_t)(b * SEQ + j0 + krow) * HDIM + n * HEADD + kc8));
        *(uint4*)&Vt_s[vrow][vc8] =
            *(const uint4*)(vT + ((size_t)((b * NHEAD + n) * HEADD + vrow) * SEQ + j0 + vc8));
        __syncthreads();

        // ---- score MFMAs ----
        f32x4 accS[2] = {};
        if (w < 2) {
            #pragma unroll
            for (int ct = 0; ct < 2; ++ct) {
                s16x8 kb0 = *(const s16x8*)&K_s[ct * 16 + colA][kg8];
                s16x8 kb1 = *(const s16x8*)&K_s[ct * 16 + colA][kg8 + 32];
                accS[ct] = MFMA(qa0, kb0, accS[ct], 0, 0, 0);
                accS[ct] = MFMA(qa1, kb1, accS[ct], 0, 0, 0);
            }
        } else {
            const int wr = w - 2;
            const int base2 = SEQ + j0 - i0 - 31;
            const int base3 = SEQ + i0 - j0 - 31;
            s16x8 ka0 = *(const s16x8*)&K_s[wr * 16 + colA][kg8];
            s16x8 ka1 = *(const s16x8*)&K_s[wr * 16 + colA][kg8 + 32];
            #pragma unroll
            for (int ut = 0; ut < 4; ++ut) {
                int urow = ut * 16 + colA;
                int l2 = base2 + urow; if (l2 > RELN - 1) l2 = RELN - 1;
                const s16x8* rp2 = (const s16x8*)(relbf + (size_t)l2 * HEADD);
                s16x8 rb0 = rp2[g], rb1 = rp2[g + 4];
                f32x4 c2 = {};
                c2 = MFMA(qb0, rb0, c2, 0, 0, 0);
                c2 = MFMA(qb1, rb1, c2, 0, 0, 0);
                ushort4 p2;
                p2.x = f2bf(c2[0]); p2.y = f2bf(c2[1]); p2.z = f2bf(c2[2]); p2.w = f2bf(c2[3]);
                *(ushort4*)&M2t_s[urow][wr * 16 + g * 4] = p2;
                int l3 = base3 + urow; if (l3 > RELN - 1) l3 = RELN - 1;
                const s16x8* rp3 = (const s16x8*)(relbf + (size_t)l3 * HEADD);
                s16x8 sb0 = rp3[g], sb1 = rp3[g + 4];
                f32x4 c3 = {};
                c3 = MFMA(ka0, sb0, c3, 0, 0, 0);
                c3 = MFMA(ka1, sb1, c3, 0, 0, 0);
                ushort4 p3;
                p3.x = f2bf(c3[0]); p3.y = f2bf(c3[1]); p3.z = f2bf(c3[2]); p3.w = f2bf(c3[3]);
                *(ushort4*)&M3t_s[urow][wr * 16 + g * 4] = p3;
            }
        }
        __syncthreads();

        // ---- softmax (W0/W1 only; rows orow..orow+15, full 32 cols) ----
        if (w < 2) {
            float sv[2][4];
            #pragma unroll
            for (int ct = 0; ct < 2; ++ct) {
                int col = ct * 16 + colA;
                bool ok = (j0 + col) < S;
                #pragma unroll
                for (int rr = 0; rr < 4; ++rr) {
                    int grow = orow + g * 4 + rr;
                    float s2 = bf2f(M2t_s[col - grow + 31][grow]);
                    float s3 = bf2f(M3t_s[grow - col + 31][col]);
                    float s = accS[ct][rr] + s2 + s3;
                    sv[ct][rr] = ok ? s : -1e30f;
                }
            }
            #pragma unroll
            for (int rr = 0; rr < 4; ++rr) {
                float mm = fmaxf(sv[0][rr], sv[1][rr]);
                mm = fmaxf(mm, __shfl_xor(mm, 1));
                mm = fmaxf(mm, __shfl_xor(mm, 2));
                mm = fmaxf(mm, __shfl_xor(mm, 4));
                mm = fmaxf(mm, __shfl_xor(mm, 8));
                float mnew = fmaxf(m_run[rr], mm);
                float sc = exp2f((m_run[rr] - mnew) * LOG2E);
                m_run[rr] = mnew;
                float p0 = exp2f((sv[0][rr] - mnew) * LOG2E);
                float p1 = exp2f((sv[1][rr] - mnew) * LOG2E);
                P_s[orow + g * 4 + rr][colA]      = f2bf(p0);
                P_s[orow + g * 4 + rr][16 + colA] = f2bf(p1);
                float pp = p0 + p1;
                pp += __shfl_xor(pp, 1);
                pp += __shfl_xor(pp, 2);
                pp += __shfl_xor(pp, 4);
                pp += __shfl_xor(pp, 8);
                l_run[rr] = l_run[rr] * sc + pp;
                if (colA == 0) scale_s[orow + g * 4 + rr] = sc;
            }
        }
        __syncthreads();

        // ---- PV (all waves) ----
        {
            float s0 = scale_s[orow + g * 4 + 0];
            float s1 = scale_s[orow + g * 4 + 1];
            float s2 = scale_s[orow + g * 4 + 2];
            float s3 = scale_s[orow + g * 4 + 3];
            o0[0] *= s0; o0[1] *= s1; o0[2] *= s2; o0[3] *= s3;
            o1[0] *= s0; o1[1] *= s1; o1[2] *= s2; o1[3] *= s3;
            s16x8 pa  = *(const s16x8*)&P_s[orow + colA][kg8];
            s16x8 vb0 = *(const s16x8*)&Vt_s[od + colA][kg8];
            s16x8 vb1 = *(const s16x8*)&Vt_s[od + 16 + colA][kg8];
            o0 = MFMA(pa, vb0, o0, 0, 0, 0);
            o1 = MFMA(pa, vb1, o1, 0, 0, 0);
        }
        __syncthreads();
    }

    if (w < 2 && colA == 0) {
        #pragma unroll
        for (int rr = 0; rr < 4; ++rr)
            lsum_s[orow + g * 4 + rr] = l_run[rr];
    }
    __syncthreads();
    #pragma unroll
    for (int rr = 0; rr < 4; ++rr) {
        int row = orow + g * 4 + rr;
        float inv = 1.f / lsum_s[row];
        size_t obase = (size_t)(b * SEQ + i0 + row) * HDIM + n * HEADD;
        out[obase + od + colA]      = o0[rr] * inv;
        out[obase + od + 16 + colA] = o1[rr] * inv;
    }
}

extern "C" void kernel_launch(void* const* d_in, const int* in_sizes, int n_in,
                              void* d_out, int out_size, void* d_ws, size_t ws_size,
                              hipStream_t stream) {
    (void)in_sizes; (void)n_in; (void)out_size; (void)ws_size;
    const float* query = (const float*)d_in[0];
    const float* key   = (const float*)d_in[1];
    const float* value = (const float*)d_in[2];
    const float* w_q_w = (const float*)d_in[3];
    const float* w_q_b = (const float*)d_in[4];
    const float* w_v_w = (const float*)d_in[5];
    const float* w_v_b = (const float*)d_in[6];
    const float* w_r_w = (const float*)d_in[7];
    const float* w_r_b = (const float*)d_in[8];
    const float* rrb   = (const float*)d_in[9];
    const float* rwb   = (const float*)d_in[10];
    const int*   seqp  = (const int*)d_in[11];
    float* out = (float*)d_out;

    unsigned short* wsp = (unsigned short*)d_ws;
    const size_t NTOK = (size_t)BATCH * SEQ * HDIM;   // 2M
    unsigned short* relbf  = wsp;
    unsigned short* kbf    = relbf + (size_t)RELN * HEADD;
    unsigned short* qabf   = kbf + NTOK;
    unsigned short* qbbf   = qabf + NTOK;
    unsigned short* vTbuf  = qbbf + NTOK;
    unsigned short* wtq_hi = vTbuf + NTOK;
    unsigned short* wtq_lo = wtq_hi + (size_t)HDIM * HDIM;
    unsigned short* wtv_hi = wtq_lo + (size_t)HDIM * HDIM;
    unsigned short* wtv_lo = wtv_hi + (size_t)HDIM * HDIM;

    hipLaunchKernelGGL(prep_kernel, dim3(RELN + 128 + 1024), dim3(256), 0, stream,
                       w_r_w, w_r_b, key, w_q_w, w_v_w,
                       relbf, kbf, wtq_hi, wtq_lo, wtv_hi, wtv_lo);
    hipLaunchKernelGGL(proj_kernel, dim3(8, 64, 2), dim3(256), 0, stream,
                       query, value, wtq_hi, wtq_lo, wtv_hi, wtv_lo,
                       w_q_b, w_v_b, rrb, rwb, qabf, qbbf, vTbuf);
    hipLaunchKernelGGL(flash_v3, dim3(SEQ / 32, NHEAD, BATCH), dim3(256), 0, stream,
                       kbf, qabf, qbbf, vTbuf, relbf, seqp, out);
}